// Round 3
// baseline (347.836 us; speedup 1.0000x reference)
//
#include <hip/hip_runtime.h>

// ---------------------------------------------------------------------------
// GenView, round 3.
//
// Algebra (verified R1/R2): per-row softmax cancels the A=emb[row]·w1 term
// and all bias constants. Remaining:
//   q[n] = feat[n] . (W @ w2)          GEMV, 51.2 MB feat read (the BW floor)
//   B[n] = sum_{e:row=n} v[e]*q[col]   segment sum
//   t[n] = exp(B[n])
//   S[n] = sum_{e:row=n} t[col]        segment sum
//   out[e] = vori[e] + t[col]/S[row]
//
// R1/R2 showed fp32 global atomicAdd = 32 B memory-side RMW @ ~18 ops/ns
// => 1.6M atomics ~ 200 us. This round replaces the segment sums with a
// bucketed counting sort (row>>7 -> 391 buckets of 128 rows): hist + scan +
// chunk-reserved scatter builds bucket-ordered 8 B edge records; segment
// sums then run one-block-per-bucket with LDS atomics + coalesced stores.
// ---------------------------------------------------------------------------

typedef unsigned int u32;

#define RPB 128              // rows per bucket (pack: col<<7 | row&127)
#define NB_MAX 512           // max buckets (N <= 65536)

// ---------------- u2[f] = sum_h W[f,h] * mw[H+h] ----------------
__global__ void k_prep_u(const float* __restrict__ W, const float* __restrict__ mw,
                         float* __restrict__ u2, int F, int H) {
  int f = blockIdx.x * blockDim.x + threadIdx.x;
  if (f >= F) return;
  const float* wr = W + (size_t)f * H;
  float s = 0.f;
  for (int h = 0; h < H; ++h) s = fmaf(wr[h], mw[H + h], s);
  u2[f] = s;
}

// ---------------- q[r] = feat[r] . u2, F=512 compile-time ----------------
// 16 lanes per row, 4 rows per wave. u2 fragment in 32 real VGPRs.
template <int F>
__global__ void k_gemv(const float* __restrict__ feat, const float* __restrict__ u2,
                       float* __restrict__ q, int N) {
  const int lane = threadIdx.x & 63;
  const int sub  = lane & 15;              // lane within 16-lane row-group
  const int grp  = lane >> 4;              // row slot 0..3 inside wave
  const int wid  = (blockIdx.x * blockDim.x + threadIdx.x) >> 6;
  const int nw   = (gridDim.x * blockDim.x) >> 6;
  float4 uf[F / 64];
#pragma unroll
  for (int i = 0; i < F / 64; ++i)
    uf[i] = *(const float4*)(u2 + i * 64 + sub * 4);
  for (int quad = wid; quad * 4 < N; quad += nw) {
    int r = quad * 4 + grp;
    float a = 0.f;
    if (r < N) {
      const float* fr = feat + (size_t)r * F;
#pragma unroll
      for (int i = 0; i < F / 64; ++i) {
        float4 v = *(const float4*)(fr + i * 64 + sub * 4);
        a = fmaf(v.x, uf[i].x, fmaf(v.y, uf[i].y,
            fmaf(v.z, uf[i].z, fmaf(v.w, uf[i].w, a))));
      }
    }
    a += __shfl_xor(a, 8);
    a += __shfl_xor(a, 4);
    a += __shfl_xor(a, 2);
    a += __shfl_xor(a, 1);
    if (sub == 0 && r < N) q[r] = a;
  }
}

// ---------------- histogram of row>>7 into cnt[nb] ----------------
__global__ void k_hist(const int* __restrict__ row, int E, int chunk,
                       u32* __restrict__ cnt, int nb) {
  __shared__ u32 h[NB_MAX];
  const int tid = threadIdx.x;
  for (int s = tid; s < nb; s += blockDim.x) h[s] = 0;
  __syncthreads();
  const int lo = blockIdx.x * chunk;
  const int hi = min(E, lo + chunk);
  for (int e = lo + tid; e < hi; e += blockDim.x)
    atomicAdd(&h[row[e] >> 7], 1u);
  __syncthreads();
  for (int s = tid; s < nb; s += blockDim.x)
    if (h[s]) atomicAdd(&cnt[s], h[s]);
}

// ---------------- exclusive scan: base[0..nb] ; rsv = base ----------------
__global__ void k_scan(const u32* __restrict__ cnt, u32* __restrict__ base,
                       u32* __restrict__ rsv, int nb) {
  __shared__ u32 s[NB_MAX];
  const int t = threadIdx.x;
  u32 v = (t < nb) ? cnt[t] : 0;
  s[t] = v;
  __syncthreads();
  for (int off = 1; off < NB_MAX; off <<= 1) {
    u32 add = (t >= off) ? s[t - off] : 0;
    __syncthreads();
    s[t] += add;
    __syncthreads();
  }
  u32 excl = s[t] - v;
  if (t <= nb) base[t] = excl;           // base[nb] = total = E
  if (t < nb) rsv[t] = excl;
}

// ---------------- scatter edges into bucket-ordered records ----------------
// record = { (col<<7) | (row&127), bits(v) }
__global__ void k_scatter(const int* __restrict__ row, const int* __restrict__ col,
                          const float* __restrict__ v, int E, int chunk,
                          u32* __restrict__ rsv, uint2* __restrict__ rec, int nb) {
  __shared__ u32 h[NB_MAX];
  __shared__ u32 start[NB_MAX];
  __shared__ u32 rk[NB_MAX];
  const int tid = threadIdx.x;
  for (int s = tid; s < nb; s += blockDim.x) { h[s] = 0; rk[s] = 0; }
  __syncthreads();
  const int lo = blockIdx.x * chunk;
  const int hi = min(E, lo + chunk);
  for (int e = lo + tid; e < hi; e += blockDim.x)
    atomicAdd(&h[row[e] >> 7], 1u);
  __syncthreads();
  for (int s = tid; s < nb; s += blockDim.x)
    if (h[s]) start[s] = atomicAdd(&rsv[s], h[s]);
  __syncthreads();
  for (int e = lo + tid; e < hi; e += blockDim.x) {
    int r = row[e];
    int b = r >> 7;
    u32 rank = atomicAdd(&rk[b], 1u);
    u32 dst = start[b] + rank;
    rec[dst] = make_uint2(((u32)col[e] << 7) | (u32)(r & 127),
                          __float_as_uint(v[e]));
  }
}

// ---------------- per-bucket segment sum (one block per bucket) ----------------
// mode 0: out[row] = sum v * g[col]   (g = q)
// mode 1: out[row] = sum g[col]       (g = t)
__global__ void k_bucket_sum(const uint2* __restrict__ rec, const u32* __restrict__ base,
                             const float* __restrict__ g, float* __restrict__ out,
                             int mode) {
  __shared__ float acc[RPB];
  const int b = blockIdx.x;
  const int tid = threadIdx.x;
  if (tid < RPB) acc[tid] = 0.f;
  __syncthreads();
  const u32 lo = base[b], hi = base[b + 1];
  for (u32 i = lo + tid; i < hi; i += blockDim.x) {
    uint2 rr = rec[i];
    int c = rr.x >> 7;
    int rlo = rr.x & 127;
    float gv = g[c];
    float val = mode ? gv : gv * __uint_as_float(rr.y);
    atomicAdd(&acc[rlo], val);
  }
  __syncthreads();
  if (tid < RPB) out[b * RPB + tid] = acc[tid];
}

// ---------------- t[n] = exp(B[n]) ----------------
__global__ void k_node_t(const float* __restrict__ B, float* __restrict__ t, int N) {
  int n = blockIdx.x * blockDim.x + threadIdx.x;
  if (n < N) t[n] = __expf(B[n]);
}

// ---------------- out[e] = vori[e] + t[col]/S[row] ----------------
__global__ void k_out(const int* __restrict__ row, const int* __restrict__ col,
                      const float* __restrict__ vori, const float* __restrict__ t,
                      const float* __restrict__ S, float* __restrict__ out, int E) {
  int e = blockIdx.x * blockDim.x + threadIdx.x;
  if (e >= E) return;
  out[e] = vori[e] + t[col[e]] / S[row[e]];
}

// ---------------- fallback scatter kernels (ws too small) ----------------
__global__ void k_scatter_B_at(const int* __restrict__ row, const int* __restrict__ col,
                               const float* __restrict__ v, const float* __restrict__ q,
                               float* __restrict__ B, int E) {
  int e = blockIdx.x * blockDim.x + threadIdx.x;
  if (e >= E) return;
  atomicAdd(&B[row[e]], v[e] * q[col[e]]);
}
__global__ void k_scatter_S_at(const int* __restrict__ row, const int* __restrict__ col,
                               const float* __restrict__ t, float* __restrict__ S, int E) {
  int e = blockIdx.x * blockDim.x + threadIdx.x;
  if (e >= E) return;
  atomicAdd(&S[row[e]], t[col[e]]);
}

extern "C" void kernel_launch(void* const* d_in, const int* in_sizes, int n_in,
                              void* d_out, int out_size, void* d_ws, size_t ws_size,
                              hipStream_t stream) {
  const float* vori = (const float*)d_in[0];
  const float* feat = (const float*)d_in[1];
  const int*   vind = (const int*)d_in[2];
  const float* W    = (const float*)d_in[4];
  const float* mw   = (const float*)d_in[6];

  const int E = in_sizes[0];
  const int H = in_sizes[6] / 2;        // 128
  const int F = in_sizes[4] / H;        // 512
  const int N = in_sizes[1] / F;        // 50000

  const int* row = vind;
  const int* col = vind + E;

  const int nb   = (N + RPB - 1) / RPB;       // 391
  const int npad = nb * RPB;

  // ---- workspace layout ----
  // floats: u2(F) | qt(N) | BS(npad)   then u32: cnt(nb) base(nb+1) rsv(nb)
  // then uint2 rec(E)
  float* ws  = (float*)d_ws;
  float* u2  = ws;
  float* qt  = ws + F;                        // q, later t (q dead before t)
  float* BS  = qt + N;                        // B, later S (B dead before S)
  u32*  cnt  = (u32*)(BS + npad);
  u32*  base = cnt + nb;
  u32*  rsv  = base + nb + 1;
  size_t hdr_bytes = (size_t)((char*)(rsv + nb) - (char*)d_ws);
  hdr_bytes = (hdr_bytes + 7) & ~(size_t)7;
  uint2* rec = (uint2*)((char*)d_ws + hdr_bytes);
  size_t need = hdr_bytes + (size_t)E * sizeof(uint2);

  const int eb = (E + 255) / 256;
  const int nbk = (N + 255) / 256;

  k_prep_u<<<(F + 255) / 256, 256, 0, stream>>>(W, mw, u2, F, H);
  k_gemv<512><<<(N + 1023) / 1024, 256, 0, stream>>>(feat, u2, qt, N);

  if (ws_size >= need && F == 512 && nb <= NB_MAX) {
    const int SBLK = 128;                     // hist/scatter blocks
    const int chunk = (E + SBLK - 1) / SBLK;
    hipMemsetAsync((void*)cnt, 0, sizeof(u32) * nb, stream);
    k_hist<<<SBLK, 256, 0, stream>>>(row, E, chunk, cnt, nb);
    k_scan<<<1, NB_MAX, 0, stream>>>(cnt, base, rsv, nb);
    k_scatter<<<SBLK, 256, 0, stream>>>(row, col, vori, E, chunk, rsv, rec, nb);
    k_bucket_sum<<<nb, 256, 0, stream>>>(rec, base, qt, BS, 0);   // B
    k_node_t<<<nbk, 256, 0, stream>>>(BS, qt, N);                 // t over q
    k_bucket_sum<<<nb, 256, 0, stream>>>(rec, base, qt, BS, 1);   // S over B
    k_out<<<eb, 256, 0, stream>>>(row, col, vori, qt, BS, (float*)d_out, E);
  } else {
    // fallback: atomic scatters (needs F + 3N floats)
    float* B = BS;                            // npad >= N
    float* t = qt;                            // reuse
    float* S = BS;                            // S overwrites B after t
    hipMemsetAsync((void*)B, 0, sizeof(float) * (size_t)npad, stream);
    k_scatter_B_at<<<eb, 256, 0, stream>>>(row, col, vori, qt, B, E);
    k_node_t<<<nbk, 256, 0, stream>>>(B, t, N);
    hipMemsetAsync((void*)S, 0, sizeof(float) * (size_t)npad, stream);
    k_scatter_S_at<<<eb, 256, 0, stream>>>(row, col, t, S, E);
    k_out<<<eb, 256, 0, stream>>>(row, col, vori, t, S, (float*)d_out, E);
  }
}

// Round 4
// 241.859 us; speedup vs baseline: 1.4382x; 1.4382x over previous
//
#include <hip/hip_runtime.h>

// ---------------------------------------------------------------------------
// GenView, round 4.
//
// Algebra (verified R1-R3): per-row softmax cancels the emb[row]·w1 term and
// all biases. Pipeline:
//   q[n] = feat[n] . (W @ w2)          GEMV, 51.2 MB feat read (the BW floor)
//   B[n] = sum_{e:row=n} v[e]*q[col]   segment sum
//   t[n] = exp(B[n])
//   S[n] = sum_{e:row=n} t[col]        segment sum
//   out[e] = vori[e] + t[col]/S[row]
//
// R3 lessons: (a) gemv grid was 49 blocks -> 2% occupancy -> 123 us; now
// 3125 blocks, one 16-lane group per row. (b) global fp32/u32 atomics run at
// ~8 ops/ns device-wide; the sort now uses ZERO global atomics: per-block
// bucket counts -> deterministic scans -> exact scatter offsets.
// Buckets: row>>7 -> 391 buckets x 128 rows; rec = (col<<7|row&127, v).
// Segment sums: one block per bucket, LDS accumulators, coalesced stores.
// ---------------------------------------------------------------------------

typedef unsigned int u32;

#define RPB     128          // rows per bucket
#define NB_MAX  512          // max buckets (N <= 65536)
#define SBLK    512          // hist/scatter grid (also scan2 block size)

// ---------------- u2[f] = sum_h W[f,h] * mw[H+h] ----------------
__global__ void k_prep_u(const float* __restrict__ W, const float* __restrict__ mw,
                         float* __restrict__ u2, int F, int H) {
  int f = blockIdx.x * blockDim.x + threadIdx.x;
  if (f >= F) return;
  const float* wr = W + (size_t)f * H;
  float s = 0.f;
  for (int h = 0; h < H; ++h) s = fmaf(wr[h], mw[H + h], s);
  u2[f] = s;
}

// ---------------- q[r] = feat[r] . u2 ; 16 lanes/row, 4 rows/wave ----------
template <int F>
__global__ void k_gemv(const float* __restrict__ feat, const float* __restrict__ u2,
                       float* __restrict__ q, int N) {
  const int lane = threadIdx.x & 63;
  const int sub  = lane & 15;
  const int grp  = lane >> 4;
  const int wid  = (blockIdx.x * blockDim.x + threadIdx.x) >> 6;
  const int r    = wid * 4 + grp;
  float4 uf[F / 64];
#pragma unroll
  for (int i = 0; i < F / 64; ++i)
    uf[i] = *(const float4*)(u2 + i * 64 + sub * 4);
  float a = 0.f;
  if (r < N) {
    const float* fr = feat + (size_t)r * F;
#pragma unroll
    for (int i = 0; i < F / 64; ++i) {
      float4 v = *(const float4*)(fr + i * 64 + sub * 4);
      a = fmaf(v.x, uf[i].x, fmaf(v.y, uf[i].y,
          fmaf(v.z, uf[i].z, fmaf(v.w, uf[i].w, a))));
    }
  }
  a += __shfl_xor(a, 8);
  a += __shfl_xor(a, 4);
  a += __shfl_xor(a, 2);
  a += __shfl_xor(a, 1);
  if (sub == 0 && r < N) q[r] = a;
}

// ---------------- per-block bucket histogram -> Ht[b][blk] ----------------
__global__ void k_hist(const int* __restrict__ row, int E, int chunk,
                       u32* __restrict__ Ht, int nb) {
  __shared__ u32 h[NB_MAX];
  for (int s = threadIdx.x; s < nb; s += blockDim.x) h[s] = 0;
  __syncthreads();
  const int lo = blockIdx.x * chunk;
  const int hi = min(E, lo + chunk);
  for (int e = lo + threadIdx.x; e < hi; e += blockDim.x)
    atomicAdd(&h[row[e] >> 7], 1u);
  __syncthreads();
  for (int s = threadIdx.x; s < nb; s += blockDim.x)
    Ht[(size_t)s * gridDim.x + blockIdx.x] = h[s];
}

// ---- per-bucket exclusive scan over blocks; Ht -> rel (in place), P[b] ----
__global__ void k_scan2(u32* __restrict__ Ht, u32* __restrict__ P) {
  __shared__ u32 a[2][SBLK];
  const int b = blockIdx.x, t = threadIdx.x;
  u32 c = Ht[(size_t)b * SBLK + t];
  a[0][t] = c;
  __syncthreads();
  int src = 0;
  for (int off = 1; off < SBLK; off <<= 1) {
    a[1 ^ src][t] = a[src][t] + ((t >= off) ? a[src][t - off] : 0);
    __syncthreads();
    src ^= 1;
  }
  u32 incl = a[src][t];
  Ht[(size_t)b * SBLK + t] = incl - c;          // rel
  if (t == SBLK - 1) P[b] = incl;               // bucket total
}

// ---------------- exclusive scan over buckets: P -> base[0..nb] ----------------
__global__ void k_scan1(const u32* __restrict__ P, u32* __restrict__ base, int nb) {
  __shared__ u32 a[2][NB_MAX];
  const int t = threadIdx.x;
  u32 c = (t < nb) ? P[t] : 0;
  a[0][t] = c;
  __syncthreads();
  int src = 0;
  for (int off = 1; off < NB_MAX; off <<= 1) {
    a[1 ^ src][t] = a[src][t] + ((t >= off) ? a[src][t - off] : 0);
    __syncthreads();
    src ^= 1;
  }
  u32 incl = a[src][t];
  if (t < nb) base[t] = incl - c;
  if (t == nb - 1) base[nb] = incl;
}

// ---------------- scatter edges into bucket-ordered records ----------------
__global__ void k_scatter(const int* __restrict__ row, const int* __restrict__ col,
                          const float* __restrict__ v, int E, int chunk,
                          const u32* __restrict__ rel, const u32* __restrict__ base,
                          uint2* __restrict__ rec, int nb) {
  __shared__ u32 start[NB_MAX];
  __shared__ u32 rk[NB_MAX];
  const int blk = blockIdx.x;
  for (int s = threadIdx.x; s < nb; s += blockDim.x) {
    start[s] = base[s] + rel[(size_t)s * SBLK + blk];
    rk[s] = 0;
  }
  __syncthreads();
  const int lo = blk * chunk;
  const int hi = min(E, lo + chunk);
  for (int e = lo + threadIdx.x; e < hi; e += blockDim.x) {
    int r = row[e];
    int b = r >> 7;
    u32 rank = atomicAdd(&rk[b], 1u);
    rec[start[b] + rank] = make_uint2(((u32)col[e] << 7) | (u32)(r & 127),
                                      __float_as_uint(v[e]));
  }
}

// ---------------- per-bucket segment sum (one block per bucket) ----------------
// mode 0: out[row] = sum v * g[col]   (g = q)
// mode 1: out[row] = sum g[col]       (g = t)
__global__ void k_bucket_sum(const uint2* __restrict__ rec, const u32* __restrict__ base,
                             const float* __restrict__ g, float* __restrict__ out,
                             int mode) {
  __shared__ float acc[RPB];
  const int b = blockIdx.x;
  const int tid = threadIdx.x;
  if (tid < RPB) acc[tid] = 0.f;
  __syncthreads();
  const u32 lo = base[b], hi = base[b + 1];
  for (u32 i = lo + tid; i < hi; i += blockDim.x) {
    uint2 rr = rec[i];
    float gv = g[rr.x >> 7];
    float val = mode ? gv : gv * __uint_as_float(rr.y);
    atomicAdd(&acc[rr.x & 127], val);
  }
  __syncthreads();
  if (tid < RPB) out[b * RPB + tid] = acc[tid];
}

// ---------------- t[n] = exp(B[n]) ----------------
__global__ void k_node_t(const float* __restrict__ B, float* __restrict__ t, int N) {
  int n = blockIdx.x * blockDim.x + threadIdx.x;
  if (n < N) t[n] = __expf(B[n]);
}

// ---------------- out[e] = vori[e] + t[col]/S[row] ----------------
__global__ void k_out(const int* __restrict__ row, const int* __restrict__ col,
                      const float* __restrict__ vori, const float* __restrict__ t,
                      const float* __restrict__ S, float* __restrict__ out, int E) {
  int e = blockIdx.x * blockDim.x + threadIdx.x;
  if (e >= E) return;
  out[e] = vori[e] + t[col[e]] / S[row[e]];
}

// ---------------- fallback (ws too small): global-atomic path ----------------
__global__ void k_scatter_B_at(const int* __restrict__ row, const int* __restrict__ col,
                               const float* __restrict__ v, const float* __restrict__ q,
                               float* __restrict__ B, int E) {
  int e = blockIdx.x * blockDim.x + threadIdx.x;
  if (e >= E) return;
  atomicAdd(&B[row[e]], v[e] * q[col[e]]);
}
__global__ void k_scatter_S_at(const int* __restrict__ row, const int* __restrict__ col,
                               const float* __restrict__ t, float* __restrict__ S, int E) {
  int e = blockIdx.x * blockDim.x + threadIdx.x;
  if (e >= E) return;
  atomicAdd(&S[row[e]], t[col[e]]);
}

extern "C" void kernel_launch(void* const* d_in, const int* in_sizes, int n_in,
                              void* d_out, int out_size, void* d_ws, size_t ws_size,
                              hipStream_t stream) {
  const float* vori = (const float*)d_in[0];
  const float* feat = (const float*)d_in[1];
  const int*   vind = (const int*)d_in[2];
  const float* W    = (const float*)d_in[4];
  const float* mw   = (const float*)d_in[6];

  const int E = in_sizes[0];
  const int H = in_sizes[6] / 2;        // 128
  const int F = in_sizes[4] / H;        // 512
  const int N = in_sizes[1] / F;        // 50000

  const int* row = vind;
  const int* col = vind + E;

  const int nb   = (N + RPB - 1) / RPB; // 391
  const int npad = nb * RPB;

  // ---- workspace: u2(F) q(N) t(N) BS(npad) | Ht(nb*SBLK) P(nb) base(nb+1) | rec(E)
  float* ws  = (float*)d_ws;
  float* u2  = ws;
  float* q   = u2 + F;
  float* t   = q + N;
  float* BS  = t + N;                   // B, later overwritten by S
  u32* Ht    = (u32*)(BS + npad);
  u32* P     = Ht + (size_t)nb * SBLK;
  u32* base  = P + nb;
  size_t hdr = (size_t)((char*)(base + nb + 1) - (char*)d_ws);
  hdr = (hdr + 7) & ~(size_t)7;
  uint2* rec = (uint2*)((char*)d_ws + hdr);
  size_t need = hdr + (size_t)E * sizeof(uint2);

  const int eb  = (E + 255) / 256;
  const int nbk = (N + 255) / 256;

  k_prep_u<<<(F + 255) / 256, 256, 0, stream>>>(W, mw, u2, F, H);
  k_gemv<512><<<(N + 15) / 16, 256, 0, stream>>>(feat, u2, q, N);   // 3125 blocks

  if (ws_size >= need && F == 512 && nb <= NB_MAX) {
    const int chunk = (E + SBLK - 1) / SBLK;                        // 1563
    k_hist<<<SBLK, 256, 0, stream>>>(row, E, chunk, Ht, nb);
    k_scan2<<<nb, SBLK, 0, stream>>>(Ht, P);
    k_scan1<<<1, NB_MAX, 0, stream>>>(P, base, nb);
    k_scatter<<<SBLK, 256, 0, stream>>>(row, col, vori, E, chunk, Ht, base, rec, nb);
    k_bucket_sum<<<nb, 256, 0, stream>>>(rec, base, q, BS, 0);      // B
    k_node_t<<<nbk, 256, 0, stream>>>(BS, t, N);
    k_bucket_sum<<<nb, 256, 0, stream>>>(rec, base, t, BS, 1);      // S
    k_out<<<eb, 256, 0, stream>>>(row, col, vori, t, BS, (float*)d_out, E);
  } else {
    // fallback: global-atomic segment sums
    hipMemsetAsync((void*)BS, 0, sizeof(float) * (size_t)npad, stream);
    k_scatter_B_at<<<eb, 256, 0, stream>>>(row, col, vori, q, BS, E);
    k_node_t<<<nbk, 256, 0, stream>>>(BS, t, N);
    hipMemsetAsync((void*)BS, 0, sizeof(float) * (size_t)npad, stream);
    k_scatter_S_at<<<eb, 256, 0, stream>>>(row, col, t, BS, E);
    k_out<<<eb, 256, 0, stream>>>(row, col, vori, t, BS, (float*)d_out, E);
  }
}